// Round 11
// baseline (246.819 us; speedup 1.0000x reference)
//
#include <hip/hip_runtime.h>
#include <math.h>

#define NN     16384
#define EE     600000
#define HIDN   128
#define NFT    32
#define NGAUSS 50
#define NLAY   6
#define TABN   8192
#define CUTF   10.0f

typedef float f32x4  __attribute__((ext_vector_type(4)));
typedef short bf16x8 __attribute__((ext_vector_type(8)));

__device__ __forceinline__ float ssp(float x) {
    // softplus(x) - log(2), numerically stable
    return fmaxf(x, 0.0f) + log1pf(__expf(-fabsf(x))) - 0.69314718055994531f;
}

__device__ __forceinline__ short f2bf(float x) {
    // f32 -> bf16 round-to-nearest-even
    union { float f; unsigned u; } v; v.f = x;
    unsigned r = v.u + 0x7fffu + ((v.u >> 16) & 1u);
    return (short)(r >> 16);
}

__device__ __forceinline__ float bf2f(unsigned u16) {
    union { unsigned u; float f; } v; v.u = u16 << 16;
    return v.f;
}

// ===================== merged setup kernel (block-range dispatch) ==========
// blocks [0, NB_TAB)        : tab build (packed bf16 pairs)
// blocks [+NB_GEO)          : edge geom -> (u, v, i0*NFT) precompute
// blocks [+NB_RP)           : row_ptr binary search
// blocks [+NB_PREP)         : weight transpose+bf16
// blocks [+NB_INIT)         : h = emb[z]; hw0 = h @ l1[0]
#define NB_TAB  (NLAY * TABN / 8)                   // 6144
#define NB_GEO  ((EE + 255) / 256)                  // 2344
#define NB_RP   ((NN + 1 + 255) / 256)              // 65
#define NB_PREP ((NLAY * 24576 + 255) / 256)        // 576
#define NB_INIT (NN / 8)                            // 2048

__global__ void setup_kernel(
        const float* __restrict__ w1, const float* __restrict__ b1,
        const float* __restrict__ w2, const float* __restrict__ b2,
        unsigned short* __restrict__ tab2b,
        const int* __restrict__ ei, const float* __restrict__ pos,
        const float* __restrict__ mask, float4* __restrict__ geo4,
        int* __restrict__ rp,
        const float* __restrict__ l2w, const float* __restrict__ lww,
        const float* __restrict__ l1w,
        short* __restrict__ l2wT, short* __restrict__ lwT,
        short* __restrict__ l1T,
        const int* __restrict__ z, const float4* __restrict__ emb4,
        float4* __restrict__ h4, unsigned short* __restrict__ hw) {
    __shared__ float sm[HIDN * NFT + 8 * HIDN];   // 20 KB, reused per branch
    const int b = blockIdx.x;
    const int t = threadIdx.x;

    if (b < NB_TAB) {
        // ------- tab: tab2b[l][ent][f] = (bf16 W[ent][f], bf16 W[ent+1][f])
        float (*ea)[NGAUSS] = (float (*)[NGAUSS])sm;
        float (*t1)[NFT] = (float (*)[NFT])(sm + 8 * NGAUSS);
        int f = t & 31, g = t >> 5;
        int id = b * 8 + g;                 // 0 .. NLAY*TABN-1 exact
        int l = id / TABN, ent = id % TABN;
        float d = ent * (CUTF / (TABN - 1));
        const float delta = CUTF / (NGAUSS - 1);
        const float coeff = -0.5f / (delta * delta);
        for (int gg = f; gg < NGAUSS; gg += 32) {
            float diff = d - gg * delta;
            ea[g][gg] = __expf(coeff * diff * diff);
        }
        __syncthreads();
        float a = b1[l * NFT + f];
        const float* w1l = w1 + l * NGAUSS * NFT;
        #pragma unroll
        for (int gg = 0; gg < NGAUSS; ++gg)
            a = fmaf(ea[g][gg], w1l[gg * NFT + f], a);
        t1[g][f] = ssp(a);
        __syncthreads();
        float c = b2[l * NFT + f];
        const float* w2l = w2 + l * NFT * NFT;
        #pragma unroll
        for (int k = 0; k < NFT; ++k)
            c = fmaf(t1[g][k], w2l[k * NFT + f], c);
        unsigned short cb = (unsigned short)f2bf(c);
        size_t idx = (size_t)id * NFT + f;
        tab2b[2 * idx] = cb;                                  // .x of ent
        if (ent > 0)         tab2b[2 * (idx - NFT) + 1] = cb; // .y of ent-1
        if (ent == TABN - 1) tab2b[2 * idx + 1] = cb;         // clamp top
    } else if (b < NB_TAB + NB_GEO) {
        // ------- edge geom + lerp precompute: (cc*(1-fr), cc*fr, i0*NFT)
        int e = (b - NB_TAB) * 256 + t;
        if (e >= EE) return;
        int s = ei[e], d2 = ei[EE + e];
        float dx = pos[s * 3 + 0] - pos[d2 * 3 + 0];
        float dy = pos[s * 3 + 1] - pos[d2 * 3 + 1];
        float dz = pos[s * 3 + 2] - pos[d2 * 3 + 2];
        float d = sqrtf(dx * dx + dy * dy + dz * dz);
        float cc = 0.5f * (cosf(d * 0.31415926535897932f) + 1.0f) * mask[e];
        float p = d * ((TABN - 1) / CUTF);
        int i0 = (int)p;
        i0 = (i0 > TABN - 2) ? (TABN - 2) : (i0 < 0 ? 0 : i0);
        float fr = p - (float)i0;
        float4 g;
        g.x = cc * (1.0f - fr);
        g.y = cc * fr;
        g.z = __int_as_float(i0 * NFT);
        g.w = 0.0f;
        geo4[e] = g;
    } else if (b < NB_TAB + NB_GEO + NB_RP) {
        // ------- row_ptr: key(e) = real ? dst[e] : INT_MAX, lower_bound
        int n = (b - NB_TAB - NB_GEO) * 256 + t;
        if (n > NN) return;
        const int* dst = ei + EE;
        int lo = 0, hi = EE;
        while (lo < hi) {
            int mid = (lo + hi) >> 1;
            int key = (mask[mid] > 0.5f) ? dst[mid] : 0x7fffffff;
            if (key < n) lo = mid + 1; else hi = mid;
        }
        rp[n] = lo;
    } else if (b < NB_TAB + NB_GEO + NB_RP + NB_PREP) {
        // ------- weight transpose + bf16
        const int per = 4096 + 16384 + 4096;   // 24576 per layer
        int id = (b - NB_TAB - NB_GEO - NB_RP) * 256 + t;
        if (id >= NLAY * per) return;
        int l = id / per, r = id % per;
        if (r < 4096) {
            int f = r >> 5, k = r & 31;
            l2wT[l * 4096 + f * 32 + k] = f2bf(l2w[l * 4096 + k * 128 + f]);
        } else if (r < 4096 + 16384) {
            int q = r - 4096; int f = q >> 7, k = q & 127;
            lwT[l * 16384 + f * 128 + k] = f2bf(lww[l * 16384 + k * 128 + f]);
        } else {
            int q = r - 20480; int f = q >> 7, k = q & 127;   // f<32, k<128
            l1T[l * 4096 + f * 128 + k] = f2bf(l1w[l * 4096 + k * 32 + f]);
        }
    } else {
        // ------- init: h = emb[z]; hw0 = h @ l1[0]  (8 nodes / block)
        float* l1s = sm;                        // 128*32 f32
        float (*hls)[HIDN] = (float (*)[HIDN])(sm + HIDN * NFT);
        int c = t & 31, nl = t >> 5;
        for (int i = t; i < HIDN * NFT / 4; i += 256)
            ((float4*)l1s)[i] = ((const float4*)l1w)[i];
        int node = (b - NB_TAB - NB_GEO - NB_RP - NB_PREP) * 8 + nl;
        float4 hv = emb4[(size_t)z[node] * 32 + c];
        h4[(size_t)node * 32 + c] = hv;
        *(float4*)(&hls[nl][c * 4]) = hv;
        __syncthreads();
        float acc = 0.0f;
        #pragma unroll 16
        for (int k = 0; k < HIDN; ++k)
            acc = fmaf(hls[nl][k], l1s[k * NFT + c], acc);
        hw[(size_t)node * NFT + c] = (unsigned short)f2bf(acc);
    }
}

// =============== fused layer: edge aggregate + node update (MFMA) ==========
// 512 thr = 8 waves, 16 nodes/block, grid NN/16 = 1024 blocks.
// __launch_bounds__(512,8): VGPR cap 64 -> 4 blocks/CU -> ALL 1024 blocks
// co-resident, 32 waves/CU.
// EDGE PHASE: wave w's two 32-lane groups each own one node (2w+p); each
// group runs 4 interleaved chains (e..e+3 step 4) -> 8 chains/wave,
// 256 concurrent chains/CU == r10's standalone edge_agg residency. m goes
// to LDS bf16 (row pad 40 -> <=2-way banks, free); no global m round-trip.
// NODE PHASE: identical to r10 (wave w = f-tile w); cw loaded AFTER phase B
// (frees 16 VGPRs under the 64 cap; issued before the barrier so latency
// hides under it).
// mfma_f32_16x16x32_bf16 layouts (m89/m91-verified):
//   A: lane(16g+r) holds A[r][8g..8g+7];  B: lane(16g+c) holds B[8g..8g+7][c]
//   C/D: col = lane&15, row = 4*(lane>>4) + reg
// xs/hs tiles XOR-swizzled: 16B-granule ^= (row&7)  (G4).
#define EDGE_BODY(EIDX, ACC)                                               \
    {                                                                      \
        int e_ = (EIDX);                                                   \
        int s_ = src[e_];                                                  \
        float4 g_ = geo4[e_];                                              \
        int i0p_ = __float_as_int(g_.z);                                   \
        unsigned tv_ = tabL[i0p_ + f];                                     \
        float w0_ = bf2f(tv_ & 0xffffu);                                   \
        float w1_ = bf2f(tv_ >> 16);                                       \
        float t_ = g_.x * w0_ + g_.y * w1_;                                \
        float hv_ = bf2f(hwin[(size_t)s_ * NFT + f]);                      \
        ACC = fmaf(hv_, t_, ACC);                                          \
    }

__global__ __launch_bounds__(512, 8) void fused_layer(
        const int* __restrict__ rp, const int* __restrict__ src,
        const float4* __restrict__ geo4, const unsigned* __restrict__ tabL,
        const unsigned short* __restrict__ hwin,
        const short* __restrict__ l2wT, const float* __restrict__ l2b,
        const short* __restrict__ lwT, const float* __restrict__ lb,
        float* __restrict__ h,
        const short* __restrict__ l1Tn, unsigned short* __restrict__ hwout) {
    __shared__ unsigned short m_lds[16][40];    // bf16, pad 40 (<=2-way banks)
    __shared__ short xs[16 * 128];              // 4 KB bf16, swizzled
    __shared__ short hs[16 * 128];              // 4 KB bf16, swizzled
    const int t  = threadIdx.x;
    const int w  = t >> 6;                      // wave 0..7 = f-tile
    const int l  = t & 63;
    const int lr = l & 15;
    const int lg = l >> 4;                      // k-group 0..3
    const int f  = l & 31;                      // feature lane (edge phase)
    const int p  = l >> 5;                      // node half (edge phase)
    const int nb = blockIdx.x << 4;             // 16 nodes per block
    const int ft = w;

    // ---- issue-early (small): phase-A weight, biases, h-old
    bf16x8 aw = *(const bf16x8*)(l2wT + (ft * 16 + lr) * 32 + lg * 8);
    float biasA = l2b[ft * 16 + lr];
    float biasB = lb[ft * 16 + lr];
    float hold[4];
    #pragma unroll
    for (int i = 0; i < 4; ++i)
        hold[i] = h[(size_t)(nb + lg * 4 + i) * HIDN + ft * 16 + lr];

    // ======== edge phase: group (w,p) owns node nb+2w+p, 4 chains =========
    {
        int n = nb + 2 * w + p;
        int r0 = rp[n], r1 = rp[n + 1];
        float acc0 = 0.0f, acc1 = 0.0f, acc2 = 0.0f, acc3 = 0.0f;
        int e = r0;
        for (; e + 3 < r1; e += 4) {
            EDGE_BODY(e,     acc0);
            EDGE_BODY(e + 1, acc1);
            EDGE_BODY(e + 2, acc2);
            EDGE_BODY(e + 3, acc3);
        }
        if (e < r1)     EDGE_BODY(e,     acc0);
        if (e + 1 < r1) EDGE_BODY(e + 1, acc1);
        if (e + 2 < r1) EDGE_BODY(e + 2, acc2);
        float acc = (acc0 + acc1) + (acc2 + acc3);
        m_lds[2 * w + p][f] = (unsigned short)f2bf(acc);
    }
    // ---- issue phase-B weights; latency hides under the barrier
    bf16x8 bw[4];
    #pragma unroll
    for (int ks = 0; ks < 4; ++ks)
        bw[ks] = *(const bf16x8*)(lwT + (ft * 16 + lr) * 128 + ks * 32 + lg * 8);
    __syncthreads();

    // ======== phase A: x = ssp(m @ l2w + l2b) ========
    bf16x8 ma = *(const bf16x8*)(&m_lds[lr][lg * 8]);
    f32x4 cA = {0.f, 0.f, 0.f, 0.f};
    cA = __builtin_amdgcn_mfma_f32_16x16x32_bf16(ma, aw, cA, 0, 0, 0);
    #pragma unroll
    for (int i = 0; i < 4; ++i) {
        int row = lg * 4 + i;
        int col = ft * 16 + lr;
        xs[row * 128 + ((col >> 3) ^ (row & 7)) * 8 + (col & 7)] = f2bf(ssp(cA[i] + biasA));
    }
    __syncthreads();

    // ======== phase B: h += x @ lw + lb  (K = 128) ========
    bf16x8 xa[4];
    #pragma unroll
    for (int ks = 0; ks < 4; ++ks)
        xa[ks] = *(const bf16x8*)(xs + lr * 128 + ((ks * 4 + lg) ^ (lr & 7)) * 8);
    f32x4 cB = {0.f, 0.f, 0.f, 0.f};
    #pragma unroll
    for (int ks = 0; ks < 4; ++ks)
        cB = __builtin_amdgcn_mfma_f32_16x16x32_bf16(xa[ks], bw[ks], cB, 0, 0, 0);
    #pragma unroll
    for (int i = 0; i < 4; ++i) {
        int node = nb + lg * 4 + i;
        int row = lg * 4 + i;
        float hv = hold[i] + cB[i] + biasB;
        h[(size_t)node * HIDN + ft * 16 + lr] = hv;
        int col = ft * 16 + lr;
        hs[row * 128 + ((col >> 3) ^ (row & 7)) * 8 + (col & 7)] = f2bf(hv);
    }

    // ======== phase C: hw_next = h_new @ l1[l+1] (bf16 out, waves 0-1) =====
    if (l1Tn != nullptr) {
        bf16x8 cw[4];
        if (w < 2) {
            #pragma unroll
            for (int ks = 0; ks < 4; ++ks)
                cw[ks] = *(const bf16x8*)(l1Tn + (w * 16 + lr) * 128 + ks * 32 + lg * 8);
        }
        __syncthreads();
        if (w < 2) {
            bf16x8 ha[4];
            #pragma unroll
            for (int ks = 0; ks < 4; ++ks)
                ha[ks] = *(const bf16x8*)(hs + lr * 128 + ((ks * 4 + lg) ^ (lr & 7)) * 8);
            f32x4 c = {0.f, 0.f, 0.f, 0.f};
            #pragma unroll
            for (int ks = 0; ks < 4; ++ks)
                c = __builtin_amdgcn_mfma_f32_16x16x32_bf16(ha[ks], cw[ks], c, 0, 0, 0);
            #pragma unroll
            for (int i = 0; i < 4; ++i) {
                int node = nb + lg * 4 + i;
                hwout[(size_t)node * NFT + w * 16 + lr] = (unsigned short)f2bf(c[i]);
            }
        }
    }
}

// ---------------------------------------------------------------------------
extern "C" void kernel_launch(void* const* d_in, const int* in_sizes, int n_in,
                              void* d_out, int out_size, void* d_ws, size_t ws_size,
                              hipStream_t stream) {
    const int*   z    = (const int*)d_in[0];
    const float* pos  = (const float*)d_in[1];
    const int*   ei   = (const int*)d_in[2];    // [2][E]
    const float* mask = (const float*)d_in[3];
    const float* emb  = (const float*)d_in[4];
    const float* w1   = (const float*)d_in[5];  // [6][50][32]
    const float* b1   = (const float*)d_in[6];  // [6][32]
    const float* w2   = (const float*)d_in[7];  // [6][32][32]
    const float* b2   = (const float*)d_in[8];  // [6][32]
    const float* l1w  = (const float*)d_in[9];  // [6][128][32]
    const float* l2w  = (const float*)d_in[10]; // [6][32][128]
    const float* l2b  = (const float*)d_in[11]; // [6][128]
    const float* lww  = (const float*)d_in[12]; // [6][128][128]
    const float* lbb  = (const float*)d_in[13]; // [6][128]
    float* h = (float*)d_out;

    char* base = (char*)d_ws;
    size_t o = 0;
    auto alloc = [&](size_t bytes) -> void* {
        void* p = base + o;
        o += (bytes + 255) & ~(size_t)255;
        return p;
    };
    int*            d_rp    = (int*)alloc((NN + 1) * sizeof(int));
    float4*         d_geo4  = (float4*)alloc((size_t)EE * sizeof(float4));
    unsigned short* d_tab2b = (unsigned short*)alloc((size_t)NLAY * TABN * NFT * 2 * sizeof(unsigned short));
    unsigned short* d_hwA   = (unsigned short*)alloc((size_t)NN * NFT * sizeof(unsigned short));
    unsigned short* d_hwB   = (unsigned short*)alloc((size_t)NN * NFT * sizeof(unsigned short));
    short*          d_l2wT  = (short*)alloc((size_t)NLAY * 4096 * sizeof(short));
    short*          d_lwT   = (short*)alloc((size_t)NLAY * 16384 * sizeof(short));
    short*          d_l1T   = (short*)alloc((size_t)NLAY * 4096 * sizeof(short));
    (void)ws_size; (void)in_sizes; (void)n_in; (void)out_size;

    setup_kernel<<<NB_TAB + NB_GEO + NB_RP + NB_PREP + NB_INIT, 256, 0, stream>>>(
        w1, b1, w2, b2, d_tab2b, ei, pos, mask, d_geo4, d_rp,
        l2w, lww, l1w, d_l2wT, d_lwT, d_l1T,
        z, (const float4*)emb, (float4*)h, d_hwA);

    for (int l = 0; l < NLAY; ++l) {
        const unsigned short* hwin  = (l & 1) ? d_hwB : d_hwA;
        unsigned short*       hwout = (l & 1) ? d_hwA : d_hwB;
        const short* l1Tn = (l + 1 < NLAY) ? (d_l1T + (size_t)(l + 1) * 4096) : nullptr;
        fused_layer<<<NN / 16, 512, 0, stream>>>(
            d_rp, ei, d_geo4, (const unsigned*)(d_tab2b + (size_t)l * TABN * NFT * 2),
            hwin, d_l2wT + (size_t)l * 4096, l2b + (size_t)l * HIDN,
            d_lwT + (size_t)l * 16384, lbb + (size_t)l * HIDN, h, l1Tn, hwout);
    }
}

// Round 12
// 179.264 us; speedup vs baseline: 1.3768x; 1.3768x over previous
//
#include <hip/hip_runtime.h>
#include <math.h>

#define NN     16384
#define EE     600000
#define HIDN   128
#define NFT    32
#define NGAUSS 50
#define NLAY   6
#define TABN   8192
#define CUTF   10.0f

typedef float f32x4  __attribute__((ext_vector_type(4)));
typedef short bf16x8 __attribute__((ext_vector_type(8)));

__device__ __forceinline__ float ssp(float x) {
    // softplus(x) - log(2), numerically stable
    return fmaxf(x, 0.0f) + log1pf(__expf(-fabsf(x))) - 0.69314718055994531f;
}

__device__ __forceinline__ short f2bf(float x) {
    // f32 -> bf16 round-to-nearest-even
    union { float f; unsigned u; } v; v.f = x;
    unsigned r = v.u + 0x7fffu + ((v.u >> 16) & 1u);
    return (short)(r >> 16);
}

__device__ __forceinline__ float bf2f(unsigned u16) {
    union { unsigned u; float f; } v; v.u = u16 << 16;
    return v.f;
}

// ===================== merged setup kernel (block-range dispatch) ==========
// blocks [0, NB_TAB)        : tab build (packed bf16 pairs)
// blocks [+NB_GEO)          : edge geom -> (u, v, i0*NFT, src*NFT)
// blocks [+NB_RP)           : row_ptr binary search
// blocks [+NB_PREP)         : weight transpose+bf16
// blocks [+NB_INIT)         : h = emb[z]; hw0 = h @ l1[0]
#define NB_TAB  (NLAY * TABN / 8)                   // 6144
#define NB_GEO  ((EE + 255) / 256)                  // 2344
#define NB_RP   ((NN + 1 + 255) / 256)              // 65
#define NB_PREP ((NLAY * 24576 + 255) / 256)        // 576
#define NB_INIT (NN / 8)                            // 2048

__global__ void setup_kernel(
        const float* __restrict__ w1, const float* __restrict__ b1,
        const float* __restrict__ w2, const float* __restrict__ b2,
        unsigned short* __restrict__ tab2b,
        const int* __restrict__ ei, const float* __restrict__ pos,
        const float* __restrict__ mask, float4* __restrict__ geo4,
        int* __restrict__ rp,
        const float* __restrict__ l2w, const float* __restrict__ lww,
        const float* __restrict__ l1w,
        short* __restrict__ l2wT, short* __restrict__ lwT,
        short* __restrict__ l1T,
        const int* __restrict__ z, const float4* __restrict__ emb4,
        float4* __restrict__ h4, unsigned short* __restrict__ hw) {
    __shared__ float sm[HIDN * NFT + 8 * HIDN];   // 20 KB, reused per branch
    const int b = blockIdx.x;
    const int t = threadIdx.x;

    if (b < NB_TAB) {
        // ------- tab: tab2b[l][ent][f] = (bf16 W[ent][f], bf16 W[ent+1][f])
        float (*ea)[NGAUSS] = (float (*)[NGAUSS])sm;
        float (*t1)[NFT] = (float (*)[NFT])(sm + 8 * NGAUSS);
        int f = t & 31, g = t >> 5;
        int id = b * 8 + g;                 // 0 .. NLAY*TABN-1 exact
        int l = id / TABN, ent = id % TABN;
        float d = ent * (CUTF / (TABN - 1));
        const float delta = CUTF / (NGAUSS - 1);
        const float coeff = -0.5f / (delta * delta);
        for (int gg = f; gg < NGAUSS; gg += 32) {
            float diff = d - gg * delta;
            ea[g][gg] = __expf(coeff * diff * diff);
        }
        __syncthreads();
        float a = b1[l * NFT + f];
        const float* w1l = w1 + l * NGAUSS * NFT;
        #pragma unroll
        for (int gg = 0; gg < NGAUSS; ++gg)
            a = fmaf(ea[g][gg], w1l[gg * NFT + f], a);
        t1[g][f] = ssp(a);
        __syncthreads();
        float c = b2[l * NFT + f];
        const float* w2l = w2 + l * NFT * NFT;
        #pragma unroll
        for (int k = 0; k < NFT; ++k)
            c = fmaf(t1[g][k], w2l[k * NFT + f], c);
        unsigned short cb = (unsigned short)f2bf(c);
        size_t idx = (size_t)id * NFT + f;
        tab2b[2 * idx] = cb;                                  // .x of ent
        if (ent > 0)         tab2b[2 * (idx - NFT) + 1] = cb; // .y of ent-1
        if (ent == TABN - 1) tab2b[2 * idx + 1] = cb;         // clamp top
    } else if (b < NB_TAB + NB_GEO) {
        // ------- edge geom + full per-edge precompute:
        //   geo4[e] = (cc*(1-fr), cc*fr, bits(i0*NFT), bits(src*NFT))
        int e = (b - NB_TAB) * 256 + t;
        if (e >= EE) return;
        int s = ei[e], d2 = ei[EE + e];
        float dx = pos[s * 3 + 0] - pos[d2 * 3 + 0];
        float dy = pos[s * 3 + 1] - pos[d2 * 3 + 1];
        float dz = pos[s * 3 + 2] - pos[d2 * 3 + 2];
        float d = sqrtf(dx * dx + dy * dy + dz * dz);
        float cc = 0.5f * (cosf(d * 0.31415926535897932f) + 1.0f) * mask[e];
        float p = d * ((TABN - 1) / CUTF);
        int i0 = (int)p;
        i0 = (i0 > TABN - 2) ? (TABN - 2) : (i0 < 0 ? 0 : i0);
        float fr = p - (float)i0;
        float4 g;
        g.x = cc * (1.0f - fr);
        g.y = cc * fr;
        g.z = __int_as_float(i0 * NFT);
        g.w = __int_as_float(s * NFT);
        geo4[e] = g;
    } else if (b < NB_TAB + NB_GEO + NB_RP) {
        // ------- row_ptr: key(e) = real ? dst[e] : INT_MAX, lower_bound
        int n = (b - NB_TAB - NB_GEO) * 256 + t;
        if (n > NN) return;
        const int* dst = ei + EE;
        int lo = 0, hi = EE;
        while (lo < hi) {
            int mid = (lo + hi) >> 1;
            int key = (mask[mid] > 0.5f) ? dst[mid] : 0x7fffffff;
            if (key < n) lo = mid + 1; else hi = mid;
        }
        rp[n] = lo;
    } else if (b < NB_TAB + NB_GEO + NB_RP + NB_PREP) {
        // ------- weight transpose + bf16
        const int per = 4096 + 16384 + 4096;   // 24576 per layer
        int id = (b - NB_TAB - NB_GEO - NB_RP) * 256 + t;
        if (id >= NLAY * per) return;
        int l = id / per, r = id % per;
        if (r < 4096) {
            int f = r >> 5, k = r & 31;
            l2wT[l * 4096 + f * 32 + k] = f2bf(l2w[l * 4096 + k * 128 + f]);
        } else if (r < 4096 + 16384) {
            int q = r - 4096; int f = q >> 7, k = q & 127;
            lwT[l * 16384 + f * 128 + k] = f2bf(lww[l * 16384 + k * 128 + f]);
        } else {
            int q = r - 20480; int f = q >> 7, k = q & 127;   // f<32, k<128
            l1T[l * 4096 + f * 128 + k] = f2bf(l1w[l * 4096 + k * 32 + f]);
        }
    } else {
        // ------- init: h = emb[z]; hw0 = h @ l1[0]  (8 nodes / block)
        float* l1s = sm;                        // 128*32 f32
        float (*hls)[HIDN] = (float (*)[HIDN])(sm + HIDN * NFT);
        int c = t & 31, nl = t >> 5;
        for (int i = t; i < HIDN * NFT / 4; i += 256)
            ((float4*)l1s)[i] = ((const float4*)l1w)[i];
        int node = (b - NB_TAB - NB_GEO - NB_RP - NB_PREP) * 8 + nl;
        float4 hv = emb4[(size_t)z[node] * 32 + c];
        h4[(size_t)node * 32 + c] = hv;
        *(float4*)(&hls[nl][c * 4]) = hv;
        __syncthreads();
        float acc = 0.0f;
        #pragma unroll 16
        for (int k = 0; k < HIDN; ++k)
            acc = fmaf(hls[nl][k], l1s[k * NFT + c], acc);
        hw[(size_t)node * NFT + c] = (unsigned short)f2bf(acc);
    }
}

// -------------------------------------------------- edge aggregate (CSR) ----
// One 64-lane wave per dst node: lane = (par, f); parity split + 8 unrolled
// independent chains, 4 named accumulators. geo4 carries EVERYTHING per edge
// (u, v, tab-offset, hw-offset) -> body = 3 loads (one broadcast 16B + two
// coalesced gathers) + ~6 VALU.
#define EDGE_BODY(EIDX, ACC)                                               \
    {                                                                      \
        int e_ = (EIDX);                                                   \
        float4 g_ = geo4[e_];                                              \
        int i0p_ = __float_as_int(g_.z);                                   \
        int hop_ = __float_as_int(g_.w);                                   \
        unsigned tv_ = tabL[i0p_ + f];                                     \
        float w0_ = bf2f(tv_ & 0xffffu);                                   \
        float w1_ = bf2f(tv_ >> 16);                                       \
        float t_ = g_.x * w0_ + g_.y * w1_;                                \
        float hv_ = bf2f(hw[hop_ + f]);                                    \
        ACC = fmaf(hv_, t_, ACC);                                          \
    }

__global__ void edge_agg(const int* __restrict__ rp,
                         const float4* __restrict__ geo4, const unsigned* __restrict__ tabL,
                         const unsigned short* __restrict__ hw,
                         unsigned short* __restrict__ m) {
    int t = threadIdx.x;
    int f = t & 31, par = (t >> 5) & 1, g = t >> 6;   // 4 nodes / 256-thr block
    int n = blockIdx.x * 4 + g;
    int r0 = rp[n], r1 = rp[n + 1];
    float acc0 = 0.0f, acc1 = 0.0f, acc2 = 0.0f, acc3 = 0.0f;
    int e = r0 + par;
    for (; e + 14 < r1; e += 16) {        // 8 independent chains
        EDGE_BODY(e,      acc0);
        EDGE_BODY(e + 2,  acc1);
        EDGE_BODY(e + 4,  acc2);
        EDGE_BODY(e + 6,  acc3);
        EDGE_BODY(e + 8,  acc0);
        EDGE_BODY(e + 10, acc1);
        EDGE_BODY(e + 12, acc2);
        EDGE_BODY(e + 14, acc3);
    }
    for (; e + 6 < r1; e += 8) {          // 4 chains
        EDGE_BODY(e,     acc0);
        EDGE_BODY(e + 2, acc1);
        EDGE_BODY(e + 4, acc2);
        EDGE_BODY(e + 6, acc3);
    }
    for (; e + 2 < r1; e += 4) {
        EDGE_BODY(e,     acc0);
        EDGE_BODY(e + 2, acc1);
    }
    if (e < r1) EDGE_BODY(e, acc0);
    float acc = (acc0 + acc1) + (acc2 + acc3);
    acc += __shfl_xor(acc, 32);
    if (par == 0) m[(size_t)n * NFT + f] = (unsigned short)f2bf(acc);
}

// --------------------------------- node update, MFMA (+ fused next-layer hw)
// x = ssp(m@l2w + l2b); h += x@lw + lb; hw_next = h_new @ l1[l+1]
// 512 threads = 8 waves; block owns THIRTY-TWO nodes (two 16-node groups);
// wave w owns f-tile w for both groups -> weight fragments amortize over 2x
// the MFMA work, weight loads + barriers halve vs r10. Grid NN/32 = 512.
// mfma_f32_16x16x32_bf16 layouts (m89/m91-verified):
//   A: lane(16g+r) holds A[r][8g..8g+7];  B: lane(16g+c) holds B[8g..8g+7][c]
//   C/D: col = lane&15, row = 4*(lane>>4) + reg
// xs/hs tiles XOR-swizzled: 16B-granule ^= (row&7)  (G4).
__global__ __launch_bounds__(512, 4) void node_update_mfma(
        const unsigned short* __restrict__ mg, const short* __restrict__ l2wT,
        const float* __restrict__ l2b, const short* __restrict__ lwT,
        const float* __restrict__ lb, float* __restrict__ h,
        const short* __restrict__ l1Tn, unsigned short* __restrict__ hwn) {
    __shared__ short xs[32 * 128];          // 8 KB bf16, swizzled
    __shared__ short hs[32 * 128];          // 8 KB bf16, swizzled
    const int t   = threadIdx.x;
    const int w   = t >> 6;                 // wave 0..7 = f-tile
    const int l   = t & 63;
    const int lr  = l & 15;
    const int lg  = l >> 4;                 // k-group 0..3
    const int nb  = blockIdx.x << 5;        // 32 nodes per block
    const int ft  = w;

    // ======== issue-early: every global load this kernel needs ========
    bf16x8 ma0 = *(const bf16x8*)(mg + (size_t)(nb + lr) * NFT + lg * 8);
    bf16x8 ma1 = *(const bf16x8*)(mg + (size_t)(nb + 16 + lr) * NFT + lg * 8);
    bf16x8 aw = *(const bf16x8*)(l2wT + (ft * 16 + lr) * 32 + lg * 8);
    bf16x8 bw[4];
    #pragma unroll
    for (int ks = 0; ks < 4; ++ks)
        bw[ks] = *(const bf16x8*)(lwT + (ft * 16 + lr) * 128 + ks * 32 + lg * 8);
    float hold0[4], hold1[4];
    #pragma unroll
    for (int i = 0; i < 4; ++i) {
        hold0[i] = h[(size_t)(nb + lg * 4 + i) * HIDN + ft * 16 + lr];
        hold1[i] = h[(size_t)(nb + 16 + lg * 4 + i) * HIDN + ft * 16 + lr];
    }
    float biasA = l2b[ft * 16 + lr];
    float biasB = lb[ft * 16 + lr];

    // ======== phase A: x = ssp(m @ l2w + l2b), both node groups ========
    f32x4 cA0 = {0.f, 0.f, 0.f, 0.f}, cA1 = {0.f, 0.f, 0.f, 0.f};
    cA0 = __builtin_amdgcn_mfma_f32_16x16x32_bf16(ma0, aw, cA0, 0, 0, 0);
    cA1 = __builtin_amdgcn_mfma_f32_16x16x32_bf16(ma1, aw, cA1, 0, 0, 0);
    #pragma unroll
    for (int i = 0; i < 4; ++i) {
        int row0 = lg * 4 + i, row1 = 16 + lg * 4 + i;
        int col = ft * 16 + lr;
        xs[row0 * 128 + ((col >> 3) ^ (row0 & 7)) * 8 + (col & 7)] = f2bf(ssp(cA0[i] + biasA));
        xs[row1 * 128 + ((col >> 3) ^ (row1 & 7)) * 8 + (col & 7)] = f2bf(ssp(cA1[i] + biasA));
    }
    __syncthreads();

    // ======== phase B: h += x @ lw + lb  (K = 128), both groups ========
    bf16x8 xa0[4], xa1[4];
    #pragma unroll
    for (int ks = 0; ks < 4; ++ks) {
        xa0[ks] = *(const bf16x8*)(xs + lr * 128 + ((ks * 4 + lg) ^ (lr & 7)) * 8);
        xa1[ks] = *(const bf16x8*)(xs + (16 + lr) * 128 + ((ks * 4 + lg) ^ (lr & 7)) * 8);
    }
    f32x4 cB0 = {0.f, 0.f, 0.f, 0.f}, cB1 = {0.f, 0.f, 0.f, 0.f};
    #pragma unroll
    for (int ks = 0; ks < 4; ++ks)
        cB0 = __builtin_amdgcn_mfma_f32_16x16x32_bf16(xa0[ks], bw[ks], cB0, 0, 0, 0);
    #pragma unroll
    for (int ks = 0; ks < 4; ++ks)
        cB1 = __builtin_amdgcn_mfma_f32_16x16x32_bf16(xa1[ks], bw[ks], cB1, 0, 0, 0);
    #pragma unroll
    for (int i = 0; i < 4; ++i) {
        int row0 = lg * 4 + i, row1 = 16 + lg * 4 + i;
        int col = ft * 16 + lr;
        float hv0 = hold0[i] + cB0[i] + biasB;
        float hv1 = hold1[i] + cB1[i] + biasB;
        h[(size_t)(nb + row0) * HIDN + col] = hv0;
        h[(size_t)(nb + row1) * HIDN + col] = hv1;
        hs[row0 * 128 + ((col >> 3) ^ (row0 & 7)) * 8 + (col & 7)] = f2bf(hv0);
        hs[row1 * 128 + ((col >> 3) ^ (row1 & 7)) * 8 + (col & 7)] = f2bf(hv1);
    }

    // ======== phase C: hw_next = h_new @ l1[l+1] (bf16 out, waves 0-1) =====
    if (l1Tn != nullptr) {
        bf16x8 cw[4];
        if (w < 2) {
            #pragma unroll
            for (int ks = 0; ks < 4; ++ks)
                cw[ks] = *(const bf16x8*)(l1Tn + (w * 16 + lr) * 128 + ks * 32 + lg * 8);
        }
        __syncthreads();
        if (w < 2) {
            bf16x8 ha0[4], ha1[4];
            #pragma unroll
            for (int ks = 0; ks < 4; ++ks) {
                ha0[ks] = *(const bf16x8*)(hs + lr * 128 + ((ks * 4 + lg) ^ (lr & 7)) * 8);
                ha1[ks] = *(const bf16x8*)(hs + (16 + lr) * 128 + ((ks * 4 + lg) ^ (lr & 7)) * 8);
            }
            f32x4 c0 = {0.f, 0.f, 0.f, 0.f}, c1 = {0.f, 0.f, 0.f, 0.f};
            #pragma unroll
            for (int ks = 0; ks < 4; ++ks)
                c0 = __builtin_amdgcn_mfma_f32_16x16x32_bf16(ha0[ks], cw[ks], c0, 0, 0, 0);
            #pragma unroll
            for (int ks = 0; ks < 4; ++ks)
                c1 = __builtin_amdgcn_mfma_f32_16x16x32_bf16(ha1[ks], cw[ks], c1, 0, 0, 0);
            #pragma unroll
            for (int i = 0; i < 4; ++i) {
                hwn[(size_t)(nb + lg * 4 + i) * NFT + w * 16 + lr] = (unsigned short)f2bf(c0[i]);
                hwn[(size_t)(nb + 16 + lg * 4 + i) * NFT + w * 16 + lr] = (unsigned short)f2bf(c1[i]);
            }
        }
    }
}

// ---------------------------------------------------------------------------
extern "C" void kernel_launch(void* const* d_in, const int* in_sizes, int n_in,
                              void* d_out, int out_size, void* d_ws, size_t ws_size,
                              hipStream_t stream) {
    const int*   z    = (const int*)d_in[0];
    const float* pos  = (const float*)d_in[1];
    const int*   ei   = (const int*)d_in[2];    // [2][E]
    const float* mask = (const float*)d_in[3];
    const float* emb  = (const float*)d_in[4];
    const float* w1   = (const float*)d_in[5];  // [6][50][32]
    const float* b1   = (const float*)d_in[6];  // [6][32]
    const float* w2   = (const float*)d_in[7];  // [6][32][32]
    const float* b2   = (const float*)d_in[8];  // [6][32]
    const float* l1w  = (const float*)d_in[9];  // [6][128][32]
    const float* l2w  = (const float*)d_in[10]; // [6][32][128]
    const float* l2b  = (const float*)d_in[11]; // [6][128]
    const float* lww  = (const float*)d_in[12]; // [6][128][128]
    const float* lbb  = (const float*)d_in[13]; // [6][128]
    float* h = (float*)d_out;

    char* base = (char*)d_ws;
    size_t o = 0;
    auto alloc = [&](size_t bytes) -> void* {
        void* p = base + o;
        o += (bytes + 255) & ~(size_t)255;
        return p;
    };
    int*            d_rp    = (int*)alloc((NN + 1) * sizeof(int));
    float4*         d_geo4  = (float4*)alloc((size_t)EE * sizeof(float4));
    unsigned short* d_tab2b = (unsigned short*)alloc((size_t)NLAY * TABN * NFT * 2 * sizeof(unsigned short));
    unsigned short* d_hwA   = (unsigned short*)alloc((size_t)NN * NFT * sizeof(unsigned short));
    unsigned short* d_hwB   = (unsigned short*)alloc((size_t)NN * NFT * sizeof(unsigned short));
    unsigned short* d_m     = (unsigned short*)alloc((size_t)NN * NFT * sizeof(unsigned short));
    short*          d_l2wT  = (short*)alloc((size_t)NLAY * 4096 * sizeof(short));
    short*          d_lwT   = (short*)alloc((size_t)NLAY * 16384 * sizeof(short));
    short*          d_l1T   = (short*)alloc((size_t)NLAY * 4096 * sizeof(short));
    (void)ws_size; (void)in_sizes; (void)n_in; (void)out_size;

    setup_kernel<<<NB_TAB + NB_GEO + NB_RP + NB_PREP + NB_INIT, 256, 0, stream>>>(
        w1, b1, w2, b2, d_tab2b, ei, pos, mask, d_geo4, d_rp,
        l2w, lww, l1w, d_l2wT, d_lwT, d_l1T,
        z, (const float4*)emb, (float4*)h, d_hwA);

    for (int l = 0; l < NLAY; ++l) {
        const unsigned short* hwin  = (l & 1) ? d_hwB : d_hwA;
        unsigned short*       hwout = (l & 1) ? d_hwA : d_hwB;
        const short* l1Tn = (l + 1 < NLAY) ? (d_l1T + (size_t)(l + 1) * 4096) : nullptr;
        edge_agg<<<NN / 4, 256, 0, stream>>>(
            d_rp, d_geo4, (const unsigned*)(d_tab2b + (size_t)l * TABN * NFT * 2),
            hwin, d_m);
        node_update_mfma<<<NN / 32, 512, 0, stream>>>(
            d_m, d_l2wT + (size_t)l * 4096, l2b + (size_t)l * HIDN,
            d_lwT + (size_t)l * 16384, lbb + (size_t)l * HIDN, h, l1Tn, hwout);
    }
}